// Round 9
// baseline (199.286 us; speedup 1.0000x reference)
//
#include <hip/hip_runtime.h>
#include <hip/hip_bf16.h>

#define T_SEQ 2048
#define D_MODEL 1024
#define N_HEADS 16

typedef _Float16 half8 __attribute__((ext_vector_type(8)));
typedef _Float16 half4 __attribute__((ext_vector_type(4)));
typedef _Float16 half2v __attribute__((ext_vector_type(2)));
typedef float floatx4 __attribute__((ext_vector_type(4)));
typedef unsigned short ushort4v __attribute__((ext_vector_type(4)));
typedef unsigned short ushort8v __attribute__((ext_vector_type(8)));

#define LOG2E 1.44269504088896f

__device__ __forceinline__ unsigned short f32_to_bf16(float f) {
  unsigned u = __builtin_bit_cast(unsigned, f);
  u = u + 0x7FFFu + ((u >> 16) & 1u);
  return (unsigned short)(u >> 16);
}
__device__ __forceinline__ float bf16_to_f32(unsigned short h) {
  unsigned u = ((unsigned)h) << 16;
  return __builtin_bit_cast(float, u);
}
__device__ __forceinline__ half2v pk_f16(float a, float b) {
  return __builtin_bit_cast(half2v, __builtin_amdgcn_cvt_pkrtz(a, b));
}

// async 16B/lane global->LDS. lds base must be wave-uniform; HW adds lane*16.
__device__ __forceinline__ void load16_lds(const _Float16* g, _Float16* lds_base, int lane) {
#if __has_builtin(__builtin_amdgcn_global_load_lds)
  __builtin_amdgcn_global_load_lds(
      (const __attribute__((address_space(1))) void*)g,
      (__attribute__((address_space(3))) void*)lds_base, 16, 0, 0);
#else
  *(half8*)(lds_base + lane * 8) = *(const half8*)g;
#endif
}

// ---------------- per-block dtype detection (replaces k_detect launch) ----------------
// Samples 256 ushorts of x, wave ballots + LDS sum. 256-thread blocks only.
// One barrier; ~20 cycles. Same decision rule as the old k_detect kernel.
__device__ __forceinline__ int detect_flag(const unsigned short* __restrict__ x) {
  __shared__ int dcnt[4];
  const int tid = threadIdx.x;
  unsigned short v = x[(size_t)(tid & 255) * 2];
  int e = (v >> 7) & 0xFF;
  int ok = (v == 0) || (e >= 100 && e <= 150);
  unsigned long long m = __ballot(ok);
  if ((tid & 63) == 0) dcnt[(tid >> 6) & 3] = (int)__popcll(m);
  __syncthreads();
  return (dcnt[0] + dcnt[1] + dcnt[2] + dcnt[3]) >= 192;
}

// ---------------- transpose (weights) + bias/mask convert, one launch ----------------
__global__ __launch_bounds__(256) void k_transpose2(
    const void* __restrict__ inA, _Float16* __restrict__ outA,
    const void* __restrict__ inB, _Float16* __restrict__ outB,
    const void* __restrict__ ba, const void* __restrict__ bp,
    const void* __restrict__ mk, float* __restrict__ baF,
    float* __restrict__ bpF, float* __restrict__ mask2,
    const unsigned short* __restrict__ xdet) {
  __shared__ float tile[32][33];
  int f = detect_flag(xdet);
  if (blockIdx.x >= 4096) {  // cvt3 tail blocks
    int i = (blockIdx.x - 4096) * 256 + threadIdx.x;
    auto cv = [&](const void* p, int j) {
      return f ? bf16_to_f32(((const unsigned short*)p)[j]) : ((const float*)p)[j];
    };
    if (i < 3072) baF[i] = cv(ba, i);
    else if (i < 4096) bpF[i - 3072] = cv(bp, i - 3072);
    else mask2[i - 4096] = cv(mk, i - 4096) * (2.0f * LOG2E);
    return;
  }
  const void* in;
  _Float16* out;
  int N, bid;
  if (blockIdx.x < 3072) { in = inA; out = outA; N = 3072; bid = blockIdx.x; }
  else { in = inB; out = outB; N = 1024; bid = blockIdx.x - 3072; }
  const int K = 1024;
  int nb = N >> 5;
  int bx = bid % nb, by = bid / nb;
  int n0 = bx << 5, k0 = by << 5;
  int c = threadIdx.x & 31, r = threadIdx.x >> 5;
  const float* fin = (const float*)in;
  const unsigned short* uin = (const unsigned short*)in;
#pragma unroll
  for (int i = 0; i < 4; ++i) {
    int kk = r + i * 8;
    size_t idx = (size_t)(k0 + kk) * N + n0 + c;
    tile[kk][c] = f ? bf16_to_f32(uin[idx]) : fin[idx];
  }
  __syncthreads();
#pragma unroll
  for (int i = 0; i < 4; ++i) {
    int nn = r + i * 8;
    out[(size_t)(n0 + nn) * K + k0 + c] = (_Float16)tile[c][nn];
  }
}

// ---------------- GEMM1: D[m][n] = sum_k A[m][k]*BT[n][k] + bias[m] ----------------
// 128x128 tile, BK=64; XOR-chunk-swizzled staging. R17 XCD mapping: bn-slice
// per XCD (j=bid&7 -> bn in {j*4..j*4+3}), so each XCD's 2MB x-slice stays
// L2-resident and B re-reads (384MB total) become L2 hits; A (6MB) streams.
// Requires gridDim.x == 32.
__global__ __launch_bounds__(256) void k_gemm(
    const _Float16* __restrict__ A, const void* __restrict__ BT,
    const float* __restrict__ bias, void* __restrict__ D0,
    void* __restrict__ D1, void* __restrict__ D2,
    int M, int N, int K, int outKind, int bRaw,
    const unsigned short* __restrict__ xdet) {
  __shared__ _Float16 As[128 * 64] __attribute__((aligned(16)));
  __shared__ _Float16 Bs[128 * 64] __attribute__((aligned(16)));
  const int tid = threadIdx.x;
  const int wave = tid >> 6, lane = tid & 63;
  const int ln = lane & 15, quad = lane >> 4;
  const int f = detect_flag(xdet);
  // bn-sliced XCD mapping: xcd j owns bn columns j*4..j*4+3, all bm
  const int bid0 = blockIdx.y * gridDim.x + blockIdx.x;
  const int xj = bid0 & 7, xt = bid0 >> 3;
  const int bn = (xj * 4 + (xt & 3)) * 128;
  const int bm = (xt >> 2) * 128;
  const int wm = (wave & 1) * 64, wn = (wave >> 1) * 64;

  const int sr = tid >> 3, scn = (tid & 7) ^ (sr & 7);
  const _Float16* Ag = A + (size_t)(bm + sr) * K + scn * 8;
  const _Float16* Bg16 = (const _Float16*)BT + (size_t)(bn + sr) * K + scn * 8;
  const float* Bg32 = (const float*)BT + (size_t)(bn + sr) * K + scn * 8;
  const unsigned short* Bgbf = (const unsigned short*)BT + (size_t)(bn + sr) * K + scn * 8;

  floatx4 acc[4][4] = {};

  for (int kt = 0; kt < K; kt += 64) {
    __syncthreads();
#pragma unroll
    for (int i = 0; i < 4; ++i)
      load16_lds(Ag + kt + (size_t)i * 32 * K, As + (wave * 64 + i * 256) * 8, lane);
    if (!bRaw) {
#pragma unroll
      for (int i = 0; i < 4; ++i)
        load16_lds(Bg16 + kt + (size_t)i * 32 * K, Bs + (wave * 64 + i * 256) * 8, lane);
    } else if (f) {  // raw bf16 input
#pragma unroll
      for (int i = 0; i < 4; ++i) {
        ushort8v u = *(const ushort8v*)(Bgbf + kt + (size_t)i * 32 * K);
        half8 o;
#pragma unroll
        for (int e = 0; e < 8; ++e) o[e] = (_Float16)bf16_to_f32(u[e]);
        *(half8*)(Bs + (size_t)(wave * 64 + i * 256 + lane) * 8) = o;
      }
    } else {  // raw fp32 input
#pragma unroll
      for (int i = 0; i < 4; ++i) {
        const float* sp = Bg32 + kt + (size_t)i * 32 * K;
        floatx4 a = *(const floatx4*)sp;
        floatx4 b = *(const floatx4*)(sp + 4);
        half8 o;
#pragma unroll
        for (int e = 0; e < 4; ++e) { o[e] = (_Float16)a[e]; o[e + 4] = (_Float16)b[e]; }
        *(half8*)(Bs + (size_t)(wave * 64 + i * 256 + lane) * 8) = o;
      }
    }
    __syncthreads();
    half8 af[4][2], bf[4][2];
#pragma unroll
    for (int i = 0; i < 4; ++i) {
      int r = wm + i * 16 + ln;
#pragma unroll
      for (int ks = 0; ks < 2; ++ks)
        af[i][ks] = *(const half8*)(As + r * 64 + ((quad + 4 * ks) ^ (r & 7)) * 8);
    }
#pragma unroll
    for (int j = 0; j < 4; ++j) {
      int r = wn + j * 16 + ln;
#pragma unroll
      for (int ks = 0; ks < 2; ++ks)
        bf[j][ks] = *(const half8*)(Bs + r * 64 + ((quad + 4 * ks) ^ (r & 7)) * 8);
    }
#pragma unroll
    for (int ks = 0; ks < 2; ++ks)
#pragma unroll
      for (int i = 0; i < 4; ++i)
#pragma unroll
        for (int j = 0; j < 4; ++j)
          acc[i][j] = __builtin_amdgcn_mfma_f32_16x16x32_f16(af[i][ks], bf[j][ks], acc[i][j], 0, 0, 0);
  }

  if (outKind == 0) {
    _Float16* Qs = (_Float16*)D0;
    _Float16* Ks = (_Float16*)D1;
    _Float16* Vt = (_Float16*)D2;
    const float qsc = 0.125f * LOG2E;  // 1/sqrt(64) and log2e folded into Q
#pragma unroll
    for (int i = 0; i < 4; ++i) {
      int rbase = bm + wm + i * 16 + quad * 4;
      int sect = rbase >> 10;
      int cfeat = rbase & 1023;
      int h = cfeat >> 6, hd = cfeat & 63;
      float bv[4];
#pragma unroll
      for (int r = 0; r < 4; ++r) bv[r] = bias[rbase + r];
#pragma unroll
      for (int j = 0; j < 4; ++j) {
        int col = bn + wn + j * 16 + ln;
        int b = col >> 11, t = col & 2047;
        size_t bh = (size_t)b * N_HEADS + h;
        float v[4];
#pragma unroll
        for (int r = 0; r < 4; ++r) v[r] = acc[i][j][r] + bv[r];
        if (sect == 0) {
          half4 q;
#pragma unroll
          for (int r = 0; r < 4; ++r) q[r] = (_Float16)(v[r] * qsc);
          *(half4*)(Qs + (bh * T_SEQ + t) * 64 + hd) = q;
        } else if (sect == 1) {
          half4 kk4;
#pragma unroll
          for (int r = 0; r < 4; ++r) kk4[r] = (_Float16)v[r];
          *(half4*)(Ks + (bh * T_SEQ + t) * 64 + hd) = kk4;
        } else {
#pragma unroll
          for (int r = 0; r < 4; ++r)
            Vt[(bh * 64 + hd + r) * T_SEQ + t] = (_Float16)v[r];
        }
      }
    }
  } else {
    int mode = f ? 2 : 1;  // 2: bf16 out, 1: fp32 out
#pragma unroll
    for (int i = 0; i < 4; ++i) {
      int rbase = bm + wm + i * 16 + quad * 4;
      float bv[4];
#pragma unroll
      for (int r = 0; r < 4; ++r) bv[r] = bias[rbase + r];
#pragma unroll
      for (int j = 0; j < 4; ++j) {
        int col = bn + wn + j * 16 + ln;
        float v[4];
#pragma unroll
        for (int r = 0; r < 4; ++r) v[r] = acc[i][j][r] + bv[r];
        if (mode == 1) {
          floatx4 o = {v[0], v[1], v[2], v[3]};
          *(floatx4*)((float*)D0 + (size_t)col * M + rbase) = o;
        } else {
          ushort4v o;
#pragma unroll
          for (int r = 0; r < 4; ++r) o[r] = f32_to_bf16(v[r]);
          *(ushort4v*)((unsigned short*)D0 + (size_t)col * M + rbase) = o;
        }
      }
    }
  }
}

// ---------------- GEMM2: 64M x 128N tile ----------------
// R17: replaces the 64^2 tile (3.9 staged B/output, 8 MFMA/K-step) with
// 64x128 (2.9 B/output, 16 MFMA/K-step). Grid (32,16)=512 = 2 blocks/CU,
// 24KB LDS. Same bn-sliced XCD mapping as GEMM1 (B=AttnH slice 1MB/XCD).
__global__ __launch_bounds__(256) void k_gemm2(
    const _Float16* __restrict__ A, const _Float16* __restrict__ BT,
    const float* __restrict__ bias, void* __restrict__ D0,
    int M, int N, int K, const unsigned short* __restrict__ xdet) {
  __shared__ _Float16 As[64 * 64] __attribute__((aligned(16)));
  __shared__ _Float16 Bs[128 * 64] __attribute__((aligned(16)));
  const int tid = threadIdx.x;
  const int wave = tid >> 6, lane = tid & 63;
  const int ln = lane & 15, quad = lane >> 4;
  const int f = detect_flag(xdet);
  const int bid0 = blockIdx.y * gridDim.x + blockIdx.x;
  const int xj = bid0 & 7, xt = bid0 >> 3;
  const int bn = (xj * 4 + (xt & 3)) * 128;
  const int bm = (xt >> 2) * 64;
  const int wm = (wave & 1) * 32, wn = (wave >> 1) * 64;

  const int sr = tid >> 3, scn = (tid & 7) ^ (sr & 7);
  const _Float16* Ag = A + (size_t)(bm + sr) * K + scn * 8;
  const _Float16* Bg = BT + (size_t)(bn + sr) * K + scn * 8;

  floatx4 acc[2][4] = {};

  for (int kt = 0; kt < K; kt += 64) {
    __syncthreads();
#pragma unroll
    for (int i = 0; i < 2; ++i)
      load16_lds(Ag + kt + (size_t)i * 32 * K, As + (wave * 64 + i * 256) * 8, lane);
#pragma unroll
    for (int i = 0; i < 4; ++i)
      load16_lds(Bg + kt + (size_t)i * 32 * K, Bs + (wave * 64 + i * 256) * 8, lane);
    __syncthreads();
    half8 af[2][2], bf[4][2];
#pragma unroll
    for (int i = 0; i < 2; ++i) {
      int r = wm + i * 16 + ln;
#pragma unroll
      for (int ks = 0; ks < 2; ++ks)
        af[i][ks] = *(const half8*)(As + r * 64 + ((quad + 4 * ks) ^ (r & 7)) * 8);
    }
#pragma unroll
    for (int j = 0; j < 4; ++j) {
      int r = wn + j * 16 + ln;
#pragma unroll
      for (int ks = 0; ks < 2; ++ks)
        bf[j][ks] = *(const half8*)(Bs + r * 64 + ((quad + 4 * ks) ^ (r & 7)) * 8);
    }
#pragma unroll
    for (int ks = 0; ks < 2; ++ks)
#pragma unroll
      for (int i = 0; i < 2; ++i)
#pragma unroll
        for (int j = 0; j < 4; ++j)
          acc[i][j] = __builtin_amdgcn_mfma_f32_16x16x32_f16(af[i][ks], bf[j][ks], acc[i][j], 0, 0, 0);
  }

  int mode = f ? 2 : 1;  // 2: bf16 out, 1: fp32 out
#pragma unroll
  for (int i = 0; i < 2; ++i) {
    int rbase = bm + wm + i * 16 + quad * 4;
    float bv[4];
#pragma unroll
    for (int r = 0; r < 4; ++r) bv[r] = bias[rbase + r];
#pragma unroll
    for (int j = 0; j < 4; ++j) {
      int col = bn + wn + j * 16 + ln;
      float v[4];
#pragma unroll
      for (int r = 0; r < 4; ++r) v[r] = acc[i][j][r] + bv[r];
      if (mode == 1) {
        floatx4 o = {v[0], v[1], v[2], v[3]};
        *(floatx4*)((float*)D0 + (size_t)col * M + rbase) = o;
      } else {
        ushort4v o;
#pragma unroll
        for (int r = 0; r < 4; ++r) o[r] = f32_to_bf16(v[r]);
        *(ushort4v*)((unsigned short*)D0 + (size_t)col * M + rbase) = o;
      }
    }
  }
}

// ---------------- flash attention (R16 structure, unchanged: verified 55us) ----------------
__global__ __launch_bounds__(256, 4) void k_flash(
    const _Float16* __restrict__ Qs, const _Float16* __restrict__ Ks,
    const _Float16* __restrict__ Vt, const float* __restrict__ mask2,
    _Float16* __restrict__ O) {
  __shared__ __attribute__((aligned(16))) char smem[40960];
  _Float16* KlB = (_Float16*)smem;             // [2][64*64] dbuf, swizzled
  _Float16* VlB = (_Float16*)(smem + 16384);   // [2][64*64] dbuf, swizzled
  float* MaskL = (float*)(smem + 32768);       // [2048] this block's mask row
  float* Red = (float*)smem;                   // [2][64][36] overlay (post-loop)

  const int tid = threadIdx.x, wave = tid >> 6, lane = tid & 63;
  const int ln = lane & 15, quad = lane >> 4;
  const int qh = wave & 1, kh = wave >> 1;
  const int id = ((blockIdx.x & 7) << 7) | (blockIdx.x >> 3);  // XCD swizzle
  const int qc = id & 31, h = (id >> 5) & 15, b = id >> 9;
  const size_t bh = (size_t)b * N_HEADS + h;
  const _Float16* Qb = Qs + bh * T_SEQ * 64;
  const _Float16* Kb = Ks + bh * T_SEQ * 64;
  const _Float16* Vb = Vt + bh * 64 * T_SEQ;
  const int q0w = qc * 64 + qh * 32;  // wave's 32-query base

  // stage mask row (2048 floats = 8KB) into LDS; covered by the t=0 barrier
  {
    const floatx4* src = (const floatx4*)(mask2 + (size_t)b * T_SEQ);
    floatx4* dst = (floatx4*)MaskL;
#pragma unroll
    for (int i = 0; i < 2; ++i) dst[tid + i * 256] = src[tid + i * 256];
  }

  // Q B-frags (fixed): qf[jq][kk] = Q[q0w + jq*16 + ln][kk*32 + quad*8 + e]
  half8 qf[2][2];
#pragma unroll
  for (int jq = 0; jq < 2; ++jq)
#pragma unroll
    for (int kk = 0; kk < 2; ++kk)
      qf[jq][kk] = *(const half8*)(Qb + (size_t)(q0w + jq * 16 + ln) * 64 + kk * 32 + quad * 8);

  // hoisted swizzled fragment byte offsets (static after unroll)
  int koff[2][2], voff[4][2];
#pragma unroll
  for (int jk = 0; jk < 2; ++jk) {
    int krow = kh * 32 + jk * 16 + ln;
    koff[jk][0] = (krow * 64 + ((quad) ^ (krow & 7)) * 8) * 2;
    koff[jk][1] = (krow * 64 + ((4 + quad) ^ (krow & 7)) * 8) * 2;
  }
#pragma unroll
  for (int jd = 0; jd < 4; ++jd) {
    int vrow = jd * 16 + ln;
    voff[jd][0] = (vrow * 64 + ((kh * 4 + 0 + (quad >> 1)) ^ (vrow & 7)) * 8 + (quad & 1) * 4) * 2;
    voff[jd][1] = (vrow * 64 + ((kh * 4 + 2 + (quad >> 1)) ^ (vrow & 7)) * 8 + (quad & 1) * 4) * 2;
  }

  floatx4 Oacc[4][2] = {};        // [jd d-group][jq]: O^T partial (wave's keys)
  float li[2] = {0.f, 0.f};

  // staging (all 4 waves cooperate)
  const int sr = tid >> 3, scn = (tid & 7) ^ (sr & 7);
  const _Float16* kp0 = Kb + (size_t)sr * 64 + scn * 8;
  const _Float16* kp1 = kp0 + 32 * 64;
  const _Float16* vp0 = Vb + (size_t)sr * T_SEQ + scn * 8;
  const _Float16* vp1 = vp0 + 32 * T_SEQ;

  // prime buffer 0
  {
    _Float16* K0 = KlB + (size_t)wave * 512;
    _Float16* V0 = VlB + (size_t)wave * 512;
    load16_lds(kp0, K0, lane);
    load16_lds(kp1, K0 + 2048, lane);
    load16_lds(vp0, V0, lane);
    load16_lds(vp1, V0 + 2048, lane);
    kp0 += 64 * 64; kp1 += 64 * 64; vp0 += 64; vp1 += 64;
  }

  for (int t = 0; t < 32; ++t) {
    const int cur = t & 1;
    __syncthreads();
    if (t + 1 < 32) {
      _Float16* K0 = KlB + (cur ^ 1) * 4096 + (size_t)wave * 512;
      _Float16* V0 = VlB + (cur ^ 1) * 4096 + (size_t)wave * 512;
      load16_lds(kp0, K0, lane);
      load16_lds(kp1, K0 + 2048, lane);
      load16_lds(vp0, V0, lane);
      load16_lds(vp1, V0 + 2048, lane);
      kp0 += 64 * 64; kp1 += 64 * 64; vp0 += 64; vp1 += 64;
    }
    const char* Kc = (const char*)KlB + cur * 8192;
    const char* Vc = (const char*)VlB + cur * 8192;
    const float* mt = MaskL + t * 64 + kh * 32 + quad * 4;  // key-indexed

    // S quadrant: s[jk][jq], keys = kh*32 + jk*16 + (quad*4 + r), q = jq*16+ln
    // C-init = mask directly (m0 == 0), shared across jq.
    floatx4 s[2][2];
    __builtin_amdgcn_s_setprio(1);
#pragma unroll
    for (int jk = 0; jk < 2; ++jk) {
      half8 kf0 = *(const half8*)(Kc + koff[jk][0]);
      half8 kf1 = *(const half8*)(Kc + koff[jk][1]);
      floatx4 mk4 = *(const floatx4*)(mt + jk * 16);  // LDS broadcast read
#pragma unroll
      for (int jq = 0; jq < 2; ++jq) {
        floatx4 z = __builtin_amdgcn_mfma_f32_16x16x32_f16(kf0, qf[jq][0], mk4, 0, 0, 0);
        z = __builtin_amdgcn_mfma_f32_16x16x32_f16(kf1, qf[jq][1], z, 0, 0, 0);
        s[jk][jq] = z;
      }
    }
    __builtin_amdgcn_s_setprio(0);

#pragma unroll
    for (int jk = 0; jk < 2; ++jk)
#pragma unroll
      for (int jq = 0; jq < 2; ++jq)
#pragma unroll
        for (int r = 0; r < 4; ++r) {
          float p = __builtin_amdgcn_exp2f(s[jk][jq][r]);
          s[jk][jq][r] = p;
          li[jq] += p;
        }

    // pack P to fp16 B-fragments IN REGISTERS (16x16x16 layout match, no LDS)
    half4 pf4[2][2];
#pragma unroll
    for (int jk = 0; jk < 2; ++jk)
#pragma unroll
      for (int jq = 0; jq < 2; ++jq) {
        half2v p01 = pk_f16(s[jk][jq][0], s[jk][jq][1]);
        half2v p23 = pk_f16(s[jk][jq][2], s[jk][jq][3]);
        pf4[jk][jq] = (half4){p01[0], p01[1], p23[0], p23[1]};
      }

    // PV: Oacc[d][q] += sum_jk V[d][key(jk)] * P[key(jk)][q], K=16 per MFMA.
    __builtin_amdgcn_s_setprio(1);
#pragma unroll
    for (int jd = 0; jd < 4; ++jd) {
      half4 vf0 = *(const half4*)(Vc + voff[jd][0]);
      half4 vf1 = *(const half4*)(Vc + voff[jd][1]);
#pragma unroll
      for (int jq = 0; jq < 2; ++jq) {
        Oacc[jd][jq] = __builtin_amdgcn_mfma_f32_16x16x16f16(vf0, pf4[0][jq], Oacc[jd][jq], 0, 0, 0);
        Oacc[jd][jq] = __builtin_amdgcn_mfma_f32_16x16x16f16(vf1, pf4[1][jq], Oacc[jd][jq], 0, 0, 0);
      }
    }
    __builtin_amdgcn_s_setprio(0);
  }

  // finish per-wave l (sum across quads = key rows)
#pragma unroll
  for (int jq = 0; jq < 2; ++jq) {
    li[jq] += __shfl_xor(li[jq], 16, 64);
    li[jq] += __shfl_xor(li[jq], 32, 64);
  }

  // cross-wave merge: kh=1 dumps partials to LDS; kh=0 merges and writes
  __syncthreads();
  float* myRed = Red + ((size_t)qh * 64 + lane) * 36;
  if (kh) {
#pragma unroll
    for (int jd = 0; jd < 4; ++jd)
#pragma unroll
      for (int jq = 0; jq < 2; ++jq)
#pragma unroll
        for (int r = 0; r < 4; ++r) myRed[jd * 8 + jq * 4 + r] = Oacc[jd][jq][r];
#pragma unroll
    for (int jq = 0; jq < 2; ++jq) myRed[32 + jq] = li[jq];
  }
  __syncthreads();
  if (!kh) {
    float inv[2];
#pragma unroll
    for (int jq = 0; jq < 2; ++jq) inv[jq] = 1.f / (li[jq] + myRed[32 + jq]);
#pragma unroll
    for (int jd = 0; jd < 4; ++jd)
#pragma unroll
      for (int jq = 0; jq < 2; ++jq) {
        half4 ov;
#pragma unroll
        for (int r = 0; r < 4; ++r) {
          float v = Oacc[jd][jq][r] + myRed[jd * 8 + jq * 4 + r];
          ov[r] = (_Float16)(v * inv[jq]);
        }
        *(half4*)(O + ((size_t)b * T_SEQ + q0w + jq * 16 + ln) * D_MODEL +
                  h * 64 + jd * 16 + quad * 4) = ov;
      }
  }
}

extern "C" void kernel_launch(void* const* d_in, const int* in_sizes, int n_in,
                              void* d_out, int out_size, void* d_ws, size_t ws_size,
                              hipStream_t stream) {
  const void* x      = d_in[0];
  const void* amask  = d_in[1];
  const void* w_attn = d_in[2];
  const void* b_attn = d_in[3];
  const void* w_proj = d_in[4];
  const void* b_proj = d_in[5];
  const unsigned short* xdet = (const unsigned short*)x;

  char* ws = (char*)d_ws;
  size_t off = 0;
  auto alloc = [&](size_t bytes) {
    void* p = ws + off;
    off += (bytes + 255) & ~(size_t)255;
    return p;
  };
  _Float16* WaT    = (_Float16*)alloc((size_t)3072 * 1024 * 2);
  _Float16* WpT    = (_Float16*)alloc((size_t)1024 * 1024 * 2);
  float* baF       = (float*)alloc(3072 * 4);
  float* bpF       = (float*)alloc(1024 * 4);
  float* mask2     = (float*)alloc(4096 * 4);
  _Float16* Qs     = (_Float16*)alloc((size_t)4096 * 1024 * 2);
  _Float16* Ks     = (_Float16*)alloc((size_t)4096 * 1024 * 2);
  _Float16* Vt     = (_Float16*)alloc((size_t)4096 * 1024 * 2);
  _Float16* AttnH  = (_Float16*)alloc((size_t)4096 * 1024 * 2);

  k_transpose2<<<3072 + 1024 + 32, 256, 0, stream>>>(
      w_attn, WaT, w_proj, WpT, b_attn, b_proj, amask, baF, bpF, mask2, xdet);

  // GEMM1: qkv^T = WaT(3072xK) . x(4096xK)^T (B converted in staging), fused
  // scatter to Qs/Ks/Vt
  dim3 g1(4096 / 128, 3072 / 128);
  k_gemm<<<g1, 256, 0, stream>>>(WaT, x, baF, Qs, Ks, Vt, 3072, 4096, 1024, 0, 1, xdet);

  k_flash<<<1024, 256, 0, stream>>>(Qs, Ks, Vt, mask2, AttnH);

  // GEMM2: out^T = WpT(1024xK) . AttnH(4096xK)^T -> d_out [t][1024], 64x128 tiles
  dim3 g2(4096 / 128, 1024 / 64);
  k_gemm2<<<g2, 256, 0, stream>>>(WpT, AttnH, bpF, d_out, 1024, 4096, 1024, xdet);
}

// Round 10
// 192.861 us; speedup vs baseline: 1.0333x; 1.0333x over previous
//
#include <hip/hip_runtime.h>
#include <hip/hip_bf16.h>

#define T_SEQ 2048
#define D_MODEL 1024
#define N_HEADS 16

typedef _Float16 half8 __attribute__((ext_vector_type(8)));
typedef _Float16 half4 __attribute__((ext_vector_type(4)));
typedef _Float16 half2v __attribute__((ext_vector_type(2)));
typedef float floatx4 __attribute__((ext_vector_type(4)));
typedef unsigned short ushort4v __attribute__((ext_vector_type(4)));
typedef unsigned short ushort8v __attribute__((ext_vector_type(8)));

#define LOG2E 1.44269504088896f

__device__ __forceinline__ unsigned short f32_to_bf16(float f) {
  unsigned u = __builtin_bit_cast(unsigned, f);
  u = u + 0x7FFFu + ((u >> 16) & 1u);
  return (unsigned short)(u >> 16);
}
__device__ __forceinline__ float bf16_to_f32(unsigned short h) {
  unsigned u = ((unsigned)h) << 16;
  return __builtin_bit_cast(float, u);
}
__device__ __forceinline__ half2v pk_f16(float a, float b) {
  return __builtin_bit_cast(half2v, __builtin_amdgcn_cvt_pkrtz(a, b));
}

// async 16B/lane global->LDS. lds base must be wave-uniform; HW adds lane*16.
__device__ __forceinline__ void load16_lds(const _Float16* g, _Float16* lds_base, int lane) {
#if __has_builtin(__builtin_amdgcn_global_load_lds)
  __builtin_amdgcn_global_load_lds(
      (const __attribute__((address_space(1))) void*)g,
      (__attribute__((address_space(3))) void*)lds_base, 16, 0, 0);
#else
  *(half8*)(lds_base + lane * 8) = *(const half8*)g;
#endif
}

// ---------------- per-block dtype detection (replaces k_detect launch) ----------------
// Samples 256 ushorts of x, wave ballots + LDS sum. 256-thread blocks only.
__device__ __forceinline__ int detect_flag(const unsigned short* __restrict__ x) {
  __shared__ int dcnt[4];
  const int tid = threadIdx.x;
  unsigned short v = x[(size_t)(tid & 255) * 2];
  int e = (v >> 7) & 0xFF;
  int ok = (v == 0) || (e >= 100 && e <= 150);
  unsigned long long m = __ballot(ok);
  if ((tid & 63) == 0) dcnt[(tid >> 6) & 3] = (int)__popcll(m);
  __syncthreads();
  return (dcnt[0] + dcnt[1] + dcnt[2] + dcnt[3]) >= 192;
}

// ---------------- transpose (weights) + bias/mask convert, one launch ----------------
__global__ __launch_bounds__(256) void k_transpose2(
    const void* __restrict__ inA, _Float16* __restrict__ outA,
    const void* __restrict__ inB, _Float16* __restrict__ outB,
    const void* __restrict__ ba, const void* __restrict__ bp,
    const void* __restrict__ mk, float* __restrict__ baF,
    float* __restrict__ bpF, float* __restrict__ mask2,
    const unsigned short* __restrict__ xdet) {
  __shared__ float tile[32][33];
  int f = detect_flag(xdet);
  if (blockIdx.x >= 4096) {  // cvt3 tail blocks
    int i = (blockIdx.x - 4096) * 256 + threadIdx.x;
    auto cv = [&](const void* p, int j) {
      return f ? bf16_to_f32(((const unsigned short*)p)[j]) : ((const float*)p)[j];
    };
    if (i < 3072) baF[i] = cv(ba, i);
    else if (i < 4096) bpF[i - 3072] = cv(bp, i - 3072);
    else mask2[i - 4096] = cv(mk, i - 4096) * (2.0f * LOG2E);
    return;
  }
  const void* in;
  _Float16* out;
  int N, bid;
  if (blockIdx.x < 3072) { in = inA; out = outA; N = 3072; bid = blockIdx.x; }
  else { in = inB; out = outB; N = 1024; bid = blockIdx.x - 3072; }
  const int K = 1024;
  int nb = N >> 5;
  int bx = bid % nb, by = bid / nb;
  int n0 = bx << 5, k0 = by << 5;
  int c = threadIdx.x & 31, r = threadIdx.x >> 5;
  const float* fin = (const float*)in;
  const unsigned short* uin = (const unsigned short*)in;
#pragma unroll
  for (int i = 0; i < 4; ++i) {
    int kk = r + i * 8;
    size_t idx = (size_t)(k0 + kk) * N + n0 + c;
    tile[kk][c] = f ? bf16_to_f32(uin[idx]) : fin[idx];
  }
  __syncthreads();
#pragma unroll
  for (int i = 0; i < 4; ++i) {
    int nn = r + i * 8;
    out[(size_t)(n0 + nn) * K + k0 + c] = (_Float16)tile[c][nn];
  }
}

// ---------------- GEMM1: D[m][n] = sum_k A[m][k]*BT[n][k] + bias[m] ----------------
// 128x128 tile, BK=64; XOR-chunk-swizzled staging. bn-sliced XCD mapping
// (xcd j owns bn columns j*4..j*4+3): 2MB x-slice per XCD stays L2-resident.
__global__ __launch_bounds__(256) void k_gemm(
    const _Float16* __restrict__ A, const void* __restrict__ BT,
    const float* __restrict__ bias, void* __restrict__ D0,
    void* __restrict__ D1, void* __restrict__ D2,
    int M, int N, int K, int outKind, int bRaw,
    const unsigned short* __restrict__ xdet) {
  __shared__ _Float16 As[128 * 64] __attribute__((aligned(16)));
  __shared__ _Float16 Bs[128 * 64] __attribute__((aligned(16)));
  const int tid = threadIdx.x;
  const int wave = tid >> 6, lane = tid & 63;
  const int ln = lane & 15, quad = lane >> 4;
  const int f = detect_flag(xdet);
  const int bid0 = blockIdx.y * gridDim.x + blockIdx.x;
  const int xj = bid0 & 7, xt = bid0 >> 3;
  const int bn = (xj * 4 + (xt & 3)) * 128;
  const int bm = (xt >> 2) * 128;
  const int wm = (wave & 1) * 64, wn = (wave >> 1) * 64;

  const int sr = tid >> 3, scn = (tid & 7) ^ (sr & 7);
  const _Float16* Ag = A + (size_t)(bm + sr) * K + scn * 8;
  const _Float16* Bg16 = (const _Float16*)BT + (size_t)(bn + sr) * K + scn * 8;
  const float* Bg32 = (const float*)BT + (size_t)(bn + sr) * K + scn * 8;
  const unsigned short* Bgbf = (const unsigned short*)BT + (size_t)(bn + sr) * K + scn * 8;

  floatx4 acc[4][4] = {};

  for (int kt = 0; kt < K; kt += 64) {
    __syncthreads();
#pragma unroll
    for (int i = 0; i < 4; ++i)
      load16_lds(Ag + kt + (size_t)i * 32 * K, As + (wave * 64 + i * 256) * 8, lane);
    if (!bRaw) {
#pragma unroll
      for (int i = 0; i < 4; ++i)
        load16_lds(Bg16 + kt + (size_t)i * 32 * K, Bs + (wave * 64 + i * 256) * 8, lane);
    } else if (f) {  // raw bf16 input
#pragma unroll
      for (int i = 0; i < 4; ++i) {
        ushort8v u = *(const ushort8v*)(Bgbf + kt + (size_t)i * 32 * K);
        half8 o;
#pragma unroll
        for (int e = 0; e < 8; ++e) o[e] = (_Float16)bf16_to_f32(u[e]);
        *(half8*)(Bs + (size_t)(wave * 64 + i * 256 + lane) * 8) = o;
      }
    } else {  // raw fp32 input
#pragma unroll
      for (int i = 0; i < 4; ++i) {
        const float* sp = Bg32 + kt + (size_t)i * 32 * K;
        floatx4 a = *(const floatx4*)sp;
        floatx4 b = *(const floatx4*)(sp + 4);
        half8 o;
#pragma unroll
        for (int e = 0; e < 4; ++e) { o[e] = (_Float16)a[e]; o[e + 4] = (_Float16)b[e]; }
        *(half8*)(Bs + (size_t)(wave * 64 + i * 256 + lane) * 8) = o;
      }
    }
    __syncthreads();
    half8 af[4][2], bf[4][2];
#pragma unroll
    for (int i = 0; i < 4; ++i) {
      int r = wm + i * 16 + ln;
#pragma unroll
      for (int ks = 0; ks < 2; ++ks)
        af[i][ks] = *(const half8*)(As + r * 64 + ((quad + 4 * ks) ^ (r & 7)) * 8);
    }
#pragma unroll
    for (int j = 0; j < 4; ++j) {
      int r = wn + j * 16 + ln;
#pragma unroll
      for (int ks = 0; ks < 2; ++ks)
        bf[j][ks] = *(const half8*)(Bs + r * 64 + ((quad + 4 * ks) ^ (r & 7)) * 8);
    }
#pragma unroll
    for (int ks = 0; ks < 2; ++ks)
#pragma unroll
      for (int i = 0; i < 4; ++i)
#pragma unroll
        for (int j = 0; j < 4; ++j)
          acc[i][j] = __builtin_amdgcn_mfma_f32_16x16x32_f16(af[i][ks], bf[j][ks], acc[i][j], 0, 0, 0);
  }

  if (outKind == 0) {
    _Float16* Qs = (_Float16*)D0;
    _Float16* Ks = (_Float16*)D1;
    _Float16* Vt = (_Float16*)D2;
    const float qsc = 0.125f * LOG2E;  // 1/sqrt(64) and log2e folded into Q
#pragma unroll
    for (int i = 0; i < 4; ++i) {
      int rbase = bm + wm + i * 16 + quad * 4;
      int sect = rbase >> 10;
      int cfeat = rbase & 1023;
      int h = cfeat >> 6, hd = cfeat & 63;
      float bv[4];
#pragma unroll
      for (int r = 0; r < 4; ++r) bv[r] = bias[rbase + r];
#pragma unroll
      for (int j = 0; j < 4; ++j) {
        int col = bn + wn + j * 16 + ln;
        int b = col >> 11, t = col & 2047;
        size_t bh = (size_t)b * N_HEADS + h;
        float v[4];
#pragma unroll
        for (int r = 0; r < 4; ++r) v[r] = acc[i][j][r] + bv[r];
        if (sect == 0) {
          half4 q;
#pragma unroll
          for (int r = 0; r < 4; ++r) q[r] = (_Float16)(v[r] * qsc);
          *(half4*)(Qs + (bh * T_SEQ + t) * 64 + hd) = q;
        } else if (sect == 1) {
          half4 kk4;
#pragma unroll
          for (int r = 0; r < 4; ++r) kk4[r] = (_Float16)v[r];
          *(half4*)(Ks + (bh * T_SEQ + t) * 64 + hd) = kk4;
        } else {
#pragma unroll
          for (int r = 0; r < 4; ++r)
            Vt[(bh * 64 + hd + r) * T_SEQ + t] = (_Float16)v[r];
        }
      }
    }
  } else {
    int mode = f ? 2 : 1;  // 2: bf16 out, 1: fp32 out
#pragma unroll
    for (int i = 0; i < 4; ++i) {
      int rbase = bm + wm + i * 16 + quad * 4;
      float bv[4];
#pragma unroll
      for (int r = 0; r < 4; ++r) bv[r] = bias[rbase + r];
#pragma unroll
      for (int j = 0; j < 4; ++j) {
        int col = bn + wn + j * 16 + ln;
        float v[4];
#pragma unroll
        for (int r = 0; r < 4; ++r) v[r] = acc[i][j][r] + bv[r];
        if (mode == 1) {
          floatx4 o = {v[0], v[1], v[2], v[3]};
          *(floatx4*)((float*)D0 + (size_t)col * M + rbase) = o;
        } else {
          ushort4v o;
#pragma unroll
          for (int r = 0; r < 4; ++r) o[r] = f32_to_bf16(v[r]);
          *(ushort4v*)((unsigned short*)D0 + (size_t)col * M + rbase) = o;
        }
      }
    }
  }
}

// ---------------- GEMM2: 64x64 tile, grid 1024 = 4 blocks/CU (R16 config) ----------------
// R18: reverted from R17's 64x128/512-block variant -- 2 blocks/CU starved it
// (same mechanism as the R12 lesson). 64^2 at 1024 blocks = 4 blocks/CU is the
// verified-good occupancy point. Linear XCD swizzle (grid 1024 = 8*128).
__global__ __launch_bounds__(256) void k_gemm64(
    const _Float16* __restrict__ A, const _Float16* __restrict__ BT,
    const float* __restrict__ bias, void* __restrict__ D0,
    int M, int N, int K, const unsigned short* __restrict__ xdet) {
  __shared__ _Float16 As[64 * 64] __attribute__((aligned(16)));
  __shared__ _Float16 Bs[64 * 64] __attribute__((aligned(16)));
  const int tid = threadIdx.x;
  const int wave = tid >> 6, lane = tid & 63;
  const int ln = lane & 15, quad = lane >> 4;
  const int f = detect_flag(xdet);
  const int nbx = gridDim.x;
  const int nwg = nbx * gridDim.y;
  const int bid0 = blockIdx.y * nbx + blockIdx.x;
  const int id = (bid0 & 7) * (nwg >> 3) + (bid0 >> 3);
  const int bm = (id / nbx) * 64, bn = (id % nbx) * 64;
  const int wm = (wave & 1) * 32, wn = (wave >> 1) * 32;

  const int sr = tid >> 3, scn = (tid & 7) ^ (sr & 7);
  const _Float16* Ag = A + (size_t)(bm + sr) * K + scn * 8;
  const _Float16* Bg = BT + (size_t)(bn + sr) * K + scn * 8;

  floatx4 acc[2][2] = {};

  for (int kt = 0; kt < K; kt += 64) {
    __syncthreads();
#pragma unroll
    for (int i = 0; i < 2; ++i) {
      load16_lds(Ag + kt + (size_t)i * 32 * K, As + (wave * 64 + i * 256) * 8, lane);
      load16_lds(Bg + kt + (size_t)i * 32 * K, Bs + (wave * 64 + i * 256) * 8, lane);
    }
    __syncthreads();
    half8 af[2][2], bf[2][2];
#pragma unroll
    for (int i = 0; i < 2; ++i) {
      int r = wm + i * 16 + ln;
#pragma unroll
      for (int ks = 0; ks < 2; ++ks)
        af[i][ks] = *(const half8*)(As + r * 64 + ((quad + 4 * ks) ^ (r & 7)) * 8);
    }
#pragma unroll
    for (int j = 0; j < 2; ++j) {
      int r = wn + j * 16 + ln;
#pragma unroll
      for (int ks = 0; ks < 2; ++ks)
        bf[j][ks] = *(const half8*)(Bs + r * 64 + ((quad + 4 * ks) ^ (r & 7)) * 8);
    }
#pragma unroll
    for (int ks = 0; ks < 2; ++ks)
#pragma unroll
      for (int i = 0; i < 2; ++i)
#pragma unroll
        for (int j = 0; j < 2; ++j)
          acc[i][j] = __builtin_amdgcn_mfma_f32_16x16x32_f16(af[i][ks], bf[j][ks], acc[i][j], 0, 0, 0);
  }

  int mode = f ? 2 : 1;  // 2: bf16 out, 1: fp32 out
#pragma unroll
  for (int i = 0; i < 2; ++i) {
    int rbase = bm + wm + i * 16 + quad * 4;
    float bv[4];
#pragma unroll
    for (int r = 0; r < 4; ++r) bv[r] = bias[rbase + r];
#pragma unroll
    for (int j = 0; j < 2; ++j) {
      int col = bn + wn + j * 16 + ln;
      float v[4];
#pragma unroll
      for (int r = 0; r < 4; ++r) v[r] = acc[i][j][r] + bv[r];
      if (mode == 1) {
        floatx4 o = {v[0], v[1], v[2], v[3]};
        *(floatx4*)((float*)D0 + (size_t)col * M + rbase) = o;
      } else {
        ushort4v o;
#pragma unroll
        for (int r = 0; r < 4; ++r) o[r] = f32_to_bf16(v[r]);
        *(ushort4v*)((unsigned short*)D0 + (size_t)col * M + rbase) = o;
      }
    }
  }
}

// ---------------- flash attention (R16 structure, frozen: verified ~55us) ----------------
__global__ __launch_bounds__(256, 4) void k_flash(
    const _Float16* __restrict__ Qs, const _Float16* __restrict__ Ks,
    const _Float16* __restrict__ Vt, const float* __restrict__ mask2,
    _Float16* __restrict__ O) {
  __shared__ __attribute__((aligned(16))) char smem[40960];
  _Float16* KlB = (_Float16*)smem;             // [2][64*64] dbuf, swizzled
  _Float16* VlB = (_Float16*)(smem + 16384);   // [2][64*64] dbuf, swizzled
  float* MaskL = (float*)(smem + 32768);       // [2048] this block's mask row
  float* Red = (float*)smem;                   // [2][64][36] overlay (post-loop)

  const int tid = threadIdx.x, wave = tid >> 6, lane = tid & 63;
  const int ln = lane & 15, quad = lane >> 4;
  const int qh = wave & 1, kh = wave >> 1;
  const int id = ((blockIdx.x & 7) << 7) | (blockIdx.x >> 3);  // XCD swizzle
  const int qc = id & 31, h = (id >> 5) & 15, b = id >> 9;
  const size_t bh = (size_t)b * N_HEADS + h;
  const _Float16* Qb = Qs + bh * T_SEQ * 64;
  const _Float16* Kb = Ks + bh * T_SEQ * 64;
  const _Float16* Vb = Vt + bh * 64 * T_SEQ;
  const int q0w = qc * 64 + qh * 32;  // wave's 32-query base

  // stage mask row (2048 floats = 8KB) into LDS; covered by the t=0 barrier
  {
    const floatx4* src = (const floatx4*)(mask2 + (size_t)b * T_SEQ);
    floatx4* dst = (floatx4*)MaskL;
#pragma unroll
    for (int i = 0; i < 2; ++i) dst[tid + i * 256] = src[tid + i * 256];
  }

  // Q B-frags (fixed): qf[jq][kk] = Q[q0w + jq*16 + ln][kk*32 + quad*8 + e]
  half8 qf[2][2];
#pragma unroll
  for (int jq = 0; jq < 2; ++jq)
#pragma unroll
    for (int kk = 0; kk < 2; ++kk)
      qf[jq][kk] = *(const half8*)(Qb + (size_t)(q0w + jq * 16 + ln) * 64 + kk * 32 + quad * 8);

  // hoisted swizzled fragment byte offsets (static after unroll)
  int koff[2][2], voff[4][2];
#pragma unroll
  for (int jk = 0; jk < 2; ++jk) {
    int krow = kh * 32 + jk * 16 + ln;
    koff[jk][0] = (krow * 64 + ((quad) ^ (krow & 7)) * 8) * 2;
    koff[jk][1] = (krow * 64 + ((4 + quad) ^ (krow & 7)) * 8) * 2;
  }
#pragma unroll
  for (int jd = 0; jd < 4; ++jd) {
    int vrow = jd * 16 + ln;
    voff[jd][0] = (vrow * 64 + ((kh * 4 + 0 + (quad >> 1)) ^ (vrow & 7)) * 8 + (quad & 1) * 4) * 2;
    voff[jd][1] = (vrow * 64 + ((kh * 4 + 2 + (quad >> 1)) ^ (vrow & 7)) * 8 + (quad & 1) * 4) * 2;
  }

  floatx4 Oacc[4][2] = {};        // [jd d-group][jq]: O^T partial (wave's keys)
  float li[2] = {0.f, 0.f};

  // staging (all 4 waves cooperate)
  const int sr = tid >> 3, scn = (tid & 7) ^ (sr & 7);
  const _Float16* kp0 = Kb + (size_t)sr * 64 + scn * 8;
  const _Float16* kp1 = kp0 + 32 * 64;
  const _Float16* vp0 = Vb + (size_t)sr * T_SEQ + scn * 8;
  const _Float16* vp1 = vp0 + 32 * T_SEQ;

  // prime buffer 0
  {
    _Float16* K0 = KlB + (size_t)wave * 512;
    _Float16* V0 = VlB + (size_t)wave * 512;
    load16_lds(kp0, K0, lane);
    load16_lds(kp1, K0 + 2048, lane);
    load16_lds(vp0, V0, lane);
    load16_lds(vp1, V0 + 2048, lane);
    kp0 += 64 * 64; kp1 += 64 * 64; vp0 += 64; vp1 += 64;
  }

  for (int t = 0; t < 32; ++t) {
    const int cur = t & 1;
    __syncthreads();
    if (t + 1 < 32) {
      _Float16* K0 = KlB + (cur ^ 1) * 4096 + (size_t)wave * 512;
      _Float16* V0 = VlB + (cur ^ 1) * 4096 + (size_t)wave * 512;
      load16_lds(kp0, K0, lane);
      load16_lds(kp1, K0 + 2048, lane);
      load16_lds(vp0, V0, lane);
      load16_lds(vp1, V0 + 2048, lane);
      kp0 += 64 * 64; kp1 += 64 * 64; vp0 += 64; vp1 += 64;
    }
    const char* Kc = (const char*)KlB + cur * 8192;
    const char* Vc = (const char*)VlB + cur * 8192;
    const float* mt = MaskL + t * 64 + kh * 32 + quad * 4;  // key-indexed

    // S quadrant: s[jk][jq], keys = kh*32 + jk*16 + (quad*4 + r), q = jq*16+ln
    // C-init = mask directly (m0 == 0), shared across jq.
    floatx4 s[2][2];
    __builtin_amdgcn_s_setprio(1);
#pragma unroll
    for (int jk = 0; jk < 2; ++jk) {
      half8 kf0 = *(const half8*)(Kc + koff[jk][0]);
      half8 kf1 = *(const half8*)(Kc + koff[jk][1]);
      floatx4 mk4 = *(const floatx4*)(mt + jk * 16);  // LDS broadcast read
#pragma unroll
      for (int jq = 0; jq < 2; ++jq) {
        floatx4 z = __builtin_amdgcn_mfma_f32_16x16x32_f16(kf0, qf[jq][0], mk4, 0, 0, 0);
        z = __builtin_amdgcn_mfma_f32_16x16x32_f16(kf1, qf[jq][1], z, 0, 0, 0);
        s[jk][jq] = z;
      }
    }
    __builtin_amdgcn_s_setprio(0);

#pragma unroll
    for (int jk = 0; jk < 2; ++jk)
#pragma unroll
      for (int jq = 0; jq < 2; ++jq)
#pragma unroll
        for (int r = 0; r < 4; ++r) {
          float p = __builtin_amdgcn_exp2f(s[jk][jq][r]);
          s[jk][jq][r] = p;
          li[jq] += p;
        }

    // pack P to fp16 B-fragments IN REGISTERS (16x16x16 layout match, no LDS)
    half4 pf4[2][2];
#pragma unroll
    for (int jk = 0; jk < 2; ++jk)
#pragma unroll
      for (int jq = 0; jq < 2; ++jq) {
        half2v p01 = pk_f16(s[jk][jq][0], s[jk][jq][1]);
        half2v p23 = pk_f16(s[jk][jq][2], s[jk][jq][3]);
        pf4[jk][jq] = (half4){p01[0], p01[1], p23[0], p23[1]};
      }

    // PV: Oacc[d][q] += sum_jk V[d][key(jk)] * P[key(jk)][q], K=16 per MFMA.
    __builtin_amdgcn_s_setprio(1);
#pragma unroll
    for (int jd = 0; jd < 4; ++jd) {
      half4 vf0 = *(const half4*)(Vc + voff[jd][0]);
      half4 vf1 = *(const half4*)(Vc + voff[jd][1]);
#pragma unroll
      for (int jq = 0; jq < 2; ++jq) {
        Oacc[jd][jq] = __builtin_amdgcn_mfma_f32_16x16x16f16(vf0, pf4[0][jq], Oacc[jd][jq], 0, 0, 0);
        Oacc[jd][jq] = __builtin_amdgcn_mfma_f32_16x16x16f16(vf1, pf4[1][jq], Oacc[jd][jq], 0, 0, 0);
      }
    }
    __builtin_amdgcn_s_setprio(0);
  }

  // finish per-wave l (sum across quads = key rows)
#pragma unroll
  for (int jq = 0; jq < 2; ++jq) {
    li[jq] += __shfl_xor(li[jq], 16, 64);
    li[jq] += __shfl_xor(li[jq], 32, 64);
  }

  // cross-wave merge: kh=1 dumps partials to LDS; kh=0 merges and writes
  __syncthreads();
  float* myRed = Red + ((size_t)qh * 64 + lane) * 36;
  if (kh) {
#pragma unroll
    for (int jd = 0; jd < 4; ++jd)
#pragma unroll
      for (int jq = 0; jq < 2; ++jq)
#pragma unroll
        for (int r = 0; r < 4; ++r) myRed[jd * 8 + jq * 4 + r] = Oacc[jd][jq][r];
#pragma unroll
    for (int jq = 0; jq < 2; ++jq) myRed[32 + jq] = li[jq];
  }
  __syncthreads();
  if (!kh) {
    float inv[2];
#pragma unroll
    for (int jq = 0; jq < 2; ++jq) inv[jq] = 1.f / (li[jq] + myRed[32 + jq]);
#pragma unroll
    for (int jd = 0; jd < 4; ++jd)
#pragma unroll
      for (int jq = 0; jq < 2; ++jq) {
        half4 ov;
#pragma unroll
        for (int r = 0; r < 4; ++r) {
          float v = Oacc[jd][jq][r] + myRed[jd * 8 + jq * 4 + r];
          ov[r] = (_Float16)(v * inv[jq]);
        }
        *(half4*)(O + ((size_t)b * T_SEQ + q0w + jq * 16 + ln) * D_MODEL +
                  h * 64 + jd * 16 + quad * 4) = ov;
      }
  }
}

extern "C" void kernel_launch(void* const* d_in, const int* in_sizes, int n_in,
                              void* d_out, int out_size, void* d_ws, size_t ws_size,
                              hipStream_t stream) {
  const void* x      = d_in[0];
  const void* amask  = d_in[1];
  const void* w_attn = d_in[2];
  const void* b_attn = d_in[3];
  const void* w_proj = d_in[4];
  const void* b_proj = d_in[5];
  const unsigned short* xdet = (const unsigned short*)x;

  char* ws = (char*)d_ws;
  size_t off = 0;
  auto alloc = [&](size_t bytes) {
    void* p = ws + off;
    off += (bytes + 255) & ~(size_t)255;
    return p;
  };
  _Float16* WaT    = (_Float16*)alloc((size_t)3072 * 1024 * 2);
  _Float16* WpT    = (_Float16*)alloc((size_t)1024 * 1024 * 2);
  float* baF       = (float*)alloc(3072 * 4);
  float* bpF       = (float*)alloc(1024 * 4);
  float* mask2     = (float*)alloc(4096 * 4);
  _Float16* Qs     = (_Float16*)alloc((size_t)4096 * 1024 * 2);
  _Float16* Ks     = (_Float16*)alloc((size_t)4096 * 1024 * 2);
  _Float16* Vt     = (_Float16*)alloc((size_t)4096 * 1024 * 2);
  _Float16* AttnH  = (_Float16*)alloc((size_t)4096 * 1024 * 2);

  k_transpose2<<<3072 + 1024 + 32, 256, 0, stream>>>(
      w_attn, WaT, w_proj, WpT, b_attn, b_proj, amask, baF, bpF, mask2, xdet);

  // GEMM1: qkv^T = WaT(3072xK) . x(4096xK)^T (B converted in staging), fused
  // scatter to Qs/Ks/Vt
  dim3 g1(4096 / 128, 3072 / 128);
  k_gemm<<<g1, 256, 0, stream>>>(WaT, x, baF, Qs, Ks, Vt, 3072, 4096, 1024, 0, 1, xdet);

  k_flash<<<1024, 256, 0, stream>>>(Qs, Ks, Vt, mask2, AttnH);

  // GEMM2: out^T = WpT(1024xK) . AttnH(4096xK)^T -> d_out [t][1024], 64^2 tiles
  dim3 g2(4096 / 64, 1024 / 64);
  k_gemm64<<<g2, 256, 0, stream>>>(WpT, AttnH, bpF, d_out, 1024, 4096, 1024, xdet);
}

// Round 11
// 186.587 us; speedup vs baseline: 1.0681x; 1.0336x over previous
//
#include <hip/hip_runtime.h>
#include <hip/hip_bf16.h>

#define T_SEQ 2048
#define D_MODEL 1024
#define N_HEADS 16

typedef _Float16 half8 __attribute__((ext_vector_type(8)));
typedef _Float16 half4 __attribute__((ext_vector_type(4)));
typedef _Float16 half2v __attribute__((ext_vector_type(2)));
typedef float floatx4 __attribute__((ext_vector_type(4)));
typedef unsigned short ushort4v __attribute__((ext_vector_type(4)));
typedef unsigned short ushort8v __attribute__((ext_vector_type(8)));

#define LOG2E 1.44269504088896f

__device__ __forceinline__ unsigned short f32_to_bf16(float f) {
  unsigned u = __builtin_bit_cast(unsigned, f);
  u = u + 0x7FFFu + ((u >> 16) & 1u);
  return (unsigned short)(u >> 16);
}
__device__ __forceinline__ float bf16_to_f32(unsigned short h) {
  unsigned u = ((unsigned)h) << 16;
  return __builtin_bit_cast(float, u);
}
__device__ __forceinline__ half2v pk_f16(float a, float b) {
  return __builtin_bit_cast(half2v, __builtin_amdgcn_cvt_pkrtz(a, b));
}

// async 16B/lane global->LDS. lds base must be wave-uniform; HW adds lane*16.
__device__ __forceinline__ void load16_lds(const _Float16* g, _Float16* lds_base, int lane) {
#if __has_builtin(__builtin_amdgcn_global_load_lds)
  __builtin_amdgcn_global_load_lds(
      (const __attribute__((address_space(1))) void*)g,
      (__attribute__((address_space(3))) void*)lds_base, 16, 0, 0);
#else
  *(half8*)(lds_base + lane * 8) = *(const half8*)g;
#endif
}

// ---------------- per-block dtype detection ----------------
// Samples 256 ushorts of x, wave ballots + LDS sum. 256-thread blocks only.
__device__ __forceinline__ int detect_flag(const unsigned short* __restrict__ x) {
  __shared__ int dcnt[4];
  const int tid = threadIdx.x;
  unsigned short v = x[(size_t)(tid & 255) * 2];
  int e = (v >> 7) & 0xFF;
  int ok = (v == 0) || (e >= 100 && e <= 150);
  unsigned long long m = __ballot(ok);
  if ((tid & 63) == 0) dcnt[(tid >> 6) & 3] = (int)__popcll(m);
  __syncthreads();
  return (dcnt[0] + dcnt[1] + dcnt[2] + dcnt[3]) >= 192;
}

// ---------------- transpose (weights) + bias/mask convert + x->fp16, one launch ----------------
// blocks <3072: w_attn transpose; <4096: w_proj transpose; <4128: bias/mask cvt;
// >=4128 (2048 blocks): x -> Xh fp16 conversion (old k_cvt_h8 body, R19: moved
// back OUT of GEMM1's K-loop so GEMM1 runs the pure-DMA m97 structure).
__global__ __launch_bounds__(256) void k_transpose2(
    const void* __restrict__ inA, _Float16* __restrict__ outA,
    const void* __restrict__ inB, _Float16* __restrict__ outB,
    const void* __restrict__ ba, const void* __restrict__ bp,
    const void* __restrict__ mk, float* __restrict__ baF,
    float* __restrict__ bpF, float* __restrict__ mask2,
    const void* __restrict__ xin, _Float16* __restrict__ Xh,
    const unsigned short* __restrict__ xdet) {
  __shared__ float tile[32][33];
  int f = detect_flag(xdet);
  if (blockIdx.x >= 4128) {  // x -> fp16 blocks (exact: 2048*256*8 = 4096*1024)
    int i = (blockIdx.x - 4128) * 256 + threadIdx.x;
    half8 o;
    if (f) {
      ushort8v u = ((const ushort8v*)xin)[i];
#pragma unroll
      for (int e = 0; e < 8; ++e) o[e] = (_Float16)bf16_to_f32(u[e]);
    } else {
      floatx4 a = ((const floatx4*)xin)[2 * i];
      floatx4 b = ((const floatx4*)xin)[2 * i + 1];
#pragma unroll
      for (int e = 0; e < 4; ++e) { o[e] = (_Float16)a[e]; o[e + 4] = (_Float16)b[e]; }
    }
    ((half8*)Xh)[i] = o;
    return;
  }
  if (blockIdx.x >= 4096) {  // cvt3 tail blocks
    int i = (blockIdx.x - 4096) * 256 + threadIdx.x;
    auto cv = [&](const void* p, int j) {
      return f ? bf16_to_f32(((const unsigned short*)p)[j]) : ((const float*)p)[j];
    };
    if (i < 3072) baF[i] = cv(ba, i);
    else if (i < 4096) bpF[i - 3072] = cv(bp, i - 3072);
    else mask2[i - 4096] = cv(mk, i - 4096) * (2.0f * LOG2E);
    return;
  }
  const void* in;
  _Float16* out;
  int N, bid;
  if (blockIdx.x < 3072) { in = inA; out = outA; N = 3072; bid = blockIdx.x; }
  else { in = inB; out = outB; N = 1024; bid = blockIdx.x - 3072; }
  const int K = 1024;
  int nb = N >> 5;
  int bx = bid % nb, by = bid / nb;
  int n0 = bx << 5, k0 = by << 5;
  int c = threadIdx.x & 31, r = threadIdx.x >> 5;
  const float* fin = (const float*)in;
  const unsigned short* uin = (const unsigned short*)in;
#pragma unroll
  for (int i = 0; i < 4; ++i) {
    int kk = r + i * 8;
    size_t idx = (size_t)(k0 + kk) * N + n0 + c;
    tile[kk][c] = f ? bf16_to_f32(uin[idx]) : fin[idx];
  }
  __syncthreads();
#pragma unroll
  for (int i = 0; i < 4; ++i) {
    int nn = r + i * 8;
    out[(size_t)(n0 + nn) * K + k0 + c] = (_Float16)tile[c][nn];
  }
}

// ---------------- GEMM1: D[m][n] = sum_k A[m][k]*BT[n][k] + bias[m] ----------------
// 128x128 tile, BK=64; XOR-chunk-swizzled staging. bn-sliced XCD mapping
// (xcd j owns bn columns j*4..j*4+3): 1MB Xh-slice per XCD stays L2-resident.
// R19: bRaw=0 path (B via global_load_lds from pre-converted Xh) -- pure m97
// structure, no in-loop conversion VALU / reg-staged ds_writes.
__global__ __launch_bounds__(256) void k_gemm(
    const _Float16* __restrict__ A, const void* __restrict__ BT,
    const float* __restrict__ bias, void* __restrict__ D0,
    void* __restrict__ D1, void* __restrict__ D2,
    int M, int N, int K, int outKind, int bRaw,
    const unsigned short* __restrict__ xdet) {
  __shared__ _Float16 As[128 * 64] __attribute__((aligned(16)));
  __shared__ _Float16 Bs[128 * 64] __attribute__((aligned(16)));
  const int tid = threadIdx.x;
  const int wave = tid >> 6, lane = tid & 63;
  const int ln = lane & 15, quad = lane >> 4;
  const int f = detect_flag(xdet);
  const int bid0 = blockIdx.y * gridDim.x + blockIdx.x;
  const int xj = bid0 & 7, xt = bid0 >> 3;
  const int bn = (xj * 4 + (xt & 3)) * 128;
  const int bm = (xt >> 2) * 128;
  const int wm = (wave & 1) * 64, wn = (wave >> 1) * 64;

  const int sr = tid >> 3, scn = (tid & 7) ^ (sr & 7);
  const _Float16* Ag = A + (size_t)(bm + sr) * K + scn * 8;
  const _Float16* Bg16 = (const _Float16*)BT + (size_t)(bn + sr) * K + scn * 8;
  const float* Bg32 = (const float*)BT + (size_t)(bn + sr) * K + scn * 8;
  const unsigned short* Bgbf = (const unsigned short*)BT + (size_t)(bn + sr) * K + scn * 8;

  floatx4 acc[4][4] = {};

  for (int kt = 0; kt < K; kt += 64) {
    __syncthreads();
#pragma unroll
    for (int i = 0; i < 4; ++i)
      load16_lds(Ag + kt + (size_t)i * 32 * K, As + (wave * 64 + i * 256) * 8, lane);
    if (!bRaw) {
#pragma unroll
      for (int i = 0; i < 4; ++i)
        load16_lds(Bg16 + kt + (size_t)i * 32 * K, Bs + (wave * 64 + i * 256) * 8, lane);
    } else if (f) {  // raw bf16 input
#pragma unroll
      for (int i = 0; i < 4; ++i) {
        ushort8v u = *(const ushort8v*)(Bgbf + kt + (size_t)i * 32 * K);
        half8 o;
#pragma unroll
        for (int e = 0; e < 8; ++e) o[e] = (_Float16)bf16_to_f32(u[e]);
        *(half8*)(Bs + (size_t)(wave * 64 + i * 256 + lane) * 8) = o;
      }
    } else {  // raw fp32 input
#pragma unroll
      for (int i = 0; i < 4; ++i) {
        const float* sp = Bg32 + kt + (size_t)i * 32 * K;
        floatx4 a = *(const floatx4*)sp;
        floatx4 b = *(const floatx4*)(sp + 4);
        half8 o;
#pragma unroll
        for (int e = 0; e < 4; ++e) { o[e] = (_Float16)a[e]; o[e + 4] = (_Float16)b[e]; }
        *(half8*)(Bs + (size_t)(wave * 64 + i * 256 + lane) * 8) = o;
      }
    }
    __syncthreads();
    half8 af[4][2], bf[4][2];
#pragma unroll
    for (int i = 0; i < 4; ++i) {
      int r = wm + i * 16 + ln;
#pragma unroll
      for (int ks = 0; ks < 2; ++ks)
        af[i][ks] = *(const half8*)(As + r * 64 + ((quad + 4 * ks) ^ (r & 7)) * 8);
    }
#pragma unroll
    for (int j = 0; j < 4; ++j) {
      int r = wn + j * 16 + ln;
#pragma unroll
      for (int ks = 0; ks < 2; ++ks)
        bf[j][ks] = *(const half8*)(Bs + r * 64 + ((quad + 4 * ks) ^ (r & 7)) * 8);
    }
#pragma unroll
    for (int ks = 0; ks < 2; ++ks)
#pragma unroll
      for (int i = 0; i < 4; ++i)
#pragma unroll
        for (int j = 0; j < 4; ++j)
          acc[i][j] = __builtin_amdgcn_mfma_f32_16x16x32_f16(af[i][ks], bf[j][ks], acc[i][j], 0, 0, 0);
  }

  if (outKind == 0) {
    _Float16* Qs = (_Float16*)D0;
    _Float16* Ks = (_Float16*)D1;
    _Float16* Vt = (_Float16*)D2;
    const float qsc = 0.125f * LOG2E;  // 1/sqrt(64) and log2e folded into Q
#pragma unroll
    for (int i = 0; i < 4; ++i) {
      int rbase = bm + wm + i * 16 + quad * 4;
      int sect = rbase >> 10;
      int cfeat = rbase & 1023;
      int h = cfeat >> 6, hd = cfeat & 63;
      float bv[4];
#pragma unroll
      for (int r = 0; r < 4; ++r) bv[r] = bias[rbase + r];
#pragma unroll
      for (int j = 0; j < 4; ++j) {
        int col = bn + wn + j * 16 + ln;
        int b = col >> 11, t = col & 2047;
        size_t bh = (size_t)b * N_HEADS + h;
        float v[4];
#pragma unroll
        for (int r = 0; r < 4; ++r) v[r] = acc[i][j][r] + bv[r];
        if (sect == 0) {
          half4 q;
#pragma unroll
          for (int r = 0; r < 4; ++r) q[r] = (_Float16)(v[r] * qsc);
          *(half4*)(Qs + (bh * T_SEQ + t) * 64 + hd) = q;
        } else if (sect == 1) {
          half4 kk4;
#pragma unroll
          for (int r = 0; r < 4; ++r) kk4[r] = (_Float16)v[r];
          *(half4*)(Ks + (bh * T_SEQ + t) * 64 + hd) = kk4;
        } else {
#pragma unroll
          for (int r = 0; r < 4; ++r)
            Vt[(bh * 64 + hd + r) * T_SEQ + t] = (_Float16)v[r];
        }
      }
    }
  } else {
    int mode = f ? 2 : 1;  // 2: bf16 out, 1: fp32 out
#pragma unroll
    for (int i = 0; i < 4; ++i) {
      int rbase = bm + wm + i * 16 + quad * 4;
      float bv[4];
#pragma unroll
      for (int r = 0; r < 4; ++r) bv[r] = bias[rbase + r];
#pragma unroll
      for (int j = 0; j < 4; ++j) {
        int col = bn + wn + j * 16 + ln;
        float v[4];
#pragma unroll
        for (int r = 0; r < 4; ++r) v[r] = acc[i][j][r] + bv[r];
        if (mode == 1) {
          floatx4 o = {v[0], v[1], v[2], v[3]};
          *(floatx4*)((float*)D0 + (size_t)col * M + rbase) = o;
        } else {
          ushort4v o;
#pragma unroll
          for (int r = 0; r < 4; ++r) o[r] = f32_to_bf16(v[r]);
          *(ushort4v*)((unsigned short*)D0 + (size_t)col * M + rbase) = o;
        }
      }
    }
  }
}

// ---------------- GEMM2: 64x64 tile, grid 1024 = 4 blocks/CU (verified R16/R18) ----------------
__global__ __launch_bounds__(256) void k_gemm64(
    const _Float16* __restrict__ A, const _Float16* __restrict__ BT,
    const float* __restrict__ bias, void* __restrict__ D0,
    int M, int N, int K, const unsigned short* __restrict__ xdet) {
  __shared__ _Float16 As[64 * 64] __attribute__((aligned(16)));
  __shared__ _Float16 Bs[64 * 64] __attribute__((aligned(16)));
  const int tid = threadIdx.x;
  const int wave = tid >> 6, lane = tid & 63;
  const int ln = lane & 15, quad = lane >> 4;
  const int f = detect_flag(xdet);
  const int nbx = gridDim.x;
  const int nwg = nbx * gridDim.y;
  const int bid0 = blockIdx.y * nbx + blockIdx.x;
  const int id = (bid0 & 7) * (nwg >> 3) + (bid0 >> 3);
  const int bm = (id / nbx) * 64, bn = (id % nbx) * 64;
  const int wm = (wave & 1) * 32, wn = (wave >> 1) * 32;

  const int sr = tid >> 3, scn = (tid & 7) ^ (sr & 7);
  const _Float16* Ag = A + (size_t)(bm + sr) * K + scn * 8;
  const _Float16* Bg = BT + (size_t)(bn + sr) * K + scn * 8;

  floatx4 acc[2][2] = {};

  for (int kt = 0; kt < K; kt += 64) {
    __syncthreads();
#pragma unroll
    for (int i = 0; i < 2; ++i) {
      load16_lds(Ag + kt + (size_t)i * 32 * K, As + (wave * 64 + i * 256) * 8, lane);
      load16_lds(Bg + kt + (size_t)i * 32 * K, Bs + (wave * 64 + i * 256) * 8, lane);
    }
    __syncthreads();
    half8 af[2][2], bf[2][2];
#pragma unroll
    for (int i = 0; i < 2; ++i) {
      int r = wm + i * 16 + ln;
#pragma unroll
      for (int ks = 0; ks < 2; ++ks)
        af[i][ks] = *(const half8*)(As + r * 64 + ((quad + 4 * ks) ^ (r & 7)) * 8);
    }
#pragma unroll
    for (int j = 0; j < 2; ++j) {
      int r = wn + j * 16 + ln;
#pragma unroll
      for (int ks = 0; ks < 2; ++ks)
        bf[j][ks] = *(const half8*)(Bs + r * 64 + ((quad + 4 * ks) ^ (r & 7)) * 8);
    }
#pragma unroll
    for (int ks = 0; ks < 2; ++ks)
#pragma unroll
      for (int i = 0; i < 2; ++i)
#pragma unroll
        for (int j = 0; j < 2; ++j)
          acc[i][j] = __builtin_amdgcn_mfma_f32_16x16x32_f16(af[i][ks], bf[j][ks], acc[i][j], 0, 0, 0);
  }

  int mode = f ? 2 : 1;  // 2: bf16 out, 1: fp32 out
#pragma unroll
  for (int i = 0; i < 2; ++i) {
    int rbase = bm + wm + i * 16 + quad * 4;
    float bv[4];
#pragma unroll
    for (int r = 0; r < 4; ++r) bv[r] = bias[rbase + r];
#pragma unroll
    for (int j = 0; j < 2; ++j) {
      int col = bn + wn + j * 16 + ln;
      float v[4];
#pragma unroll
      for (int r = 0; r < 4; ++r) v[r] = acc[i][j][r] + bv[r];
      if (mode == 1) {
        floatx4 o = {v[0], v[1], v[2], v[3]};
        *(floatx4*)((float*)D0 + (size_t)col * M + rbase) = o;
      } else {
        ushort4v o;
#pragma unroll
        for (int r = 0; r < 4; ++r) o[r] = f32_to_bf16(v[r]);
        *(ushort4v*)((unsigned short*)D0 + (size_t)col * M + rbase) = o;
      }
    }
  }
}

// ---------------- flash attention (R16 structure, frozen: verified ~55us) ----------------
__global__ __launch_bounds__(256, 4) void k_flash(
    const _Float16* __restrict__ Qs, const _Float16* __restrict__ Ks,
    const _Float16* __restrict__ Vt, const float* __restrict__ mask2,
    _Float16* __restrict__ O) {
  __shared__ __attribute__((aligned(16))) char smem[40960];
  _Float16* KlB = (_Float16*)smem;             // [2][64*64] dbuf, swizzled
  _Float16* VlB = (_Float16*)(smem + 16384);   // [2][64*64] dbuf, swizzled
  float* MaskL = (float*)(smem + 32768);       // [2048] this block's mask row
  float* Red = (float*)smem;                   // [2][64][36] overlay (post-loop)

  const int tid = threadIdx.x, wave = tid >> 6, lane = tid & 63;
  const int ln = lane & 15, quad = lane >> 4;
  const int qh = wave & 1, kh = wave >> 1;
  const int id = ((blockIdx.x & 7) << 7) | (blockIdx.x >> 3);  // XCD swizzle
  const int qc = id & 31, h = (id >> 5) & 15, b = id >> 9;
  const size_t bh = (size_t)b * N_HEADS + h;
  const _Float16* Qb = Qs + bh * T_SEQ * 64;
  const _Float16* Kb = Ks + bh * T_SEQ * 64;
  const _Float16* Vb = Vt + bh * 64 * T_SEQ;
  const int q0w = qc * 64 + qh * 32;  // wave's 32-query base

  // stage mask row (2048 floats = 8KB) into LDS; covered by the t=0 barrier
  {
    const floatx4* src = (const floatx4*)(mask2 + (size_t)b * T_SEQ);
    floatx4* dst = (floatx4*)MaskL;
#pragma unroll
    for (int i = 0; i < 2; ++i) dst[tid + i * 256] = src[tid + i * 256];
  }

  // Q B-frags (fixed): qf[jq][kk] = Q[q0w + jq*16 + ln][kk*32 + quad*8 + e]
  half8 qf[2][2];
#pragma unroll
  for (int jq = 0; jq < 2; ++jq)
#pragma unroll
    for (int kk = 0; kk < 2; ++kk)
      qf[jq][kk] = *(const half8*)(Qb + (size_t)(q0w + jq * 16 + ln) * 64 + kk * 32 + quad * 8);

  // hoisted swizzled fragment byte offsets (static after unroll)
  int koff[2][2], voff[4][2];
#pragma unroll
  for (int jk = 0; jk < 2; ++jk) {
    int krow = kh * 32 + jk * 16 + ln;
    koff[jk][0] = (krow * 64 + ((quad) ^ (krow & 7)) * 8) * 2;
    koff[jk][1] = (krow * 64 + ((4 + quad) ^ (krow & 7)) * 8) * 2;
  }
#pragma unroll
  for (int jd = 0; jd < 4; ++jd) {
    int vrow = jd * 16 + ln;
    voff[jd][0] = (vrow * 64 + ((kh * 4 + 0 + (quad >> 1)) ^ (vrow & 7)) * 8 + (quad & 1) * 4) * 2;
    voff[jd][1] = (vrow * 64 + ((kh * 4 + 2 + (quad >> 1)) ^ (vrow & 7)) * 8 + (quad & 1) * 4) * 2;
  }

  floatx4 Oacc[4][2] = {};        // [jd d-group][jq]: O^T partial (wave's keys)
  float li[2] = {0.f, 0.f};

  // staging (all 4 waves cooperate)
  const int sr = tid >> 3, scn = (tid & 7) ^ (sr & 7);
  const _Float16* kp0 = Kb + (size_t)sr * 64 + scn * 8;
  const _Float16* kp1 = kp0 + 32 * 64;
  const _Float16* vp0 = Vb + (size_t)sr * T_SEQ + scn * 8;
  const _Float16* vp1 = vp0 + 32 * T_SEQ;

  // prime buffer 0
  {
    _Float16* K0 = KlB + (size_t)wave * 512;
    _Float16* V0 = VlB + (size_t)wave * 512;
    load16_lds(kp0, K0, lane);
    load16_lds(kp1, K0 + 2048, lane);
    load16_lds(vp0, V0, lane);
    load16_lds(vp1, V0 + 2048, lane);
    kp0 += 64 * 64; kp1 += 64 * 64; vp0 += 64; vp1 += 64;
  }

  for (int t = 0; t < 32; ++t) {
    const int cur = t & 1;
    __syncthreads();
    if (t + 1 < 32) {
      _Float16* K0 = KlB + (cur ^ 1) * 4096 + (size_t)wave * 512;
      _Float16* V0 = VlB + (cur ^ 1) * 4096 + (size_t)wave * 512;
      load16_lds(kp0, K0, lane);
      load16_lds(kp1, K0 + 2048, lane);
      load16_lds(vp0, V0, lane);
      load16_lds(vp1, V0 + 2048, lane);
      kp0 += 64 * 64; kp1 += 64 * 64; vp0 += 64; vp1 += 64;
    }
    const char* Kc = (const char*)KlB + cur * 8192;
    const char* Vc = (const char*)VlB + cur * 8192;
    const float* mt = MaskL + t * 64 + kh * 32 + quad * 4;  // key-indexed

    // S quadrant: s[jk][jq], keys = kh*32 + jk*16 + (quad*4 + r), q = jq*16+ln
    // C-init = mask directly (m0 == 0), shared across jq.
    floatx4 s[2][2];
    __builtin_amdgcn_s_setprio(1);
#pragma unroll
    for (int jk = 0; jk < 2; ++jk) {
      half8 kf0 = *(const half8*)(Kc + koff[jk][0]);
      half8 kf1 = *(const half8*)(Kc + koff[jk][1]);
      floatx4 mk4 = *(const floatx4*)(mt + jk * 16);  // LDS broadcast read
#pragma unroll
      for (int jq = 0; jq < 2; ++jq) {
        floatx4 z = __builtin_amdgcn_mfma_f32_16x16x32_f16(kf0, qf[jq][0], mk4, 0, 0, 0);
        z = __builtin_amdgcn_mfma_f32_16x16x32_f16(kf1, qf[jq][1], z, 0, 0, 0);
        s[jk][jq] = z;
      }
    }
    __builtin_amdgcn_s_setprio(0);

#pragma unroll
    for (int jk = 0; jk < 2; ++jk)
#pragma unroll
      for (int jq = 0; jq < 2; ++jq)
#pragma unroll
        for (int r = 0; r < 4; ++r) {
          float p = __builtin_amdgcn_exp2f(s[jk][jq][r]);
          s[jk][jq][r] = p;
          li[jq] += p;
        }

    // pack P to fp16 B-fragments IN REGISTERS (16x16x16 layout match, no LDS)
    half4 pf4[2][2];
#pragma unroll
    for (int jk = 0; jk < 2; ++jk)
#pragma unroll
      for (int jq = 0; jq < 2; ++jq) {
        half2v p01 = pk_f16(s[jk][jq][0], s[jk][jq][1]);
        half2v p23 = pk_f16(s[jk][jq][2], s[jk][jq][3]);
        pf4[jk][jq] = (half4){p01[0], p01[1], p23[0], p23[1]};
      }

    // PV: Oacc[d][q] += sum_jk V[d][key(jk)] * P[key(jk)][q], K=16 per MFMA.
    __builtin_amdgcn_s_setprio(1);
#pragma unroll
    for (int jd = 0; jd < 4; ++jd) {
      half4 vf0 = *(const half4*)(Vc + voff[jd][0]);
      half4 vf1 = *(const half4*)(Vc + voff[jd][1]);
#pragma unroll
      for (int jq = 0; jq < 2; ++jq) {
        Oacc[jd][jq] = __builtin_amdgcn_mfma_f32_16x16x16f16(vf0, pf4[0][jq], Oacc[jd][jq], 0, 0, 0);
        Oacc[jd][jq] = __builtin_amdgcn_mfma_f32_16x16x16f16(vf1, pf4[1][jq], Oacc[jd][jq], 0, 0, 0);
      }
    }
    __builtin_amdgcn_s_setprio(0);
  }

  // finish per-wave l (sum across quads = key rows)
#pragma unroll
  for (int jq = 0; jq < 2; ++jq) {
    li[jq] += __shfl_xor(li[jq], 16, 64);
    li[jq] += __shfl_xor(li[jq], 32, 64);
  }

  // cross-wave merge: kh=1 dumps partials to LDS; kh=0 merges and writes
  __syncthreads();
  float* myRed = Red + ((size_t)qh * 64 + lane) * 36;
  if (kh) {
#pragma unroll
    for (int jd = 0; jd < 4; ++jd)
#pragma unroll
      for (int jq = 0; jq < 2; ++jq)
#pragma unroll
        for (int r = 0; r < 4; ++r) myRed[jd * 8 + jq * 4 + r] = Oacc[jd][jq][r];
#pragma unroll
    for (int jq = 0; jq < 2; ++jq) myRed[32 + jq] = li[jq];
  }
  __syncthreads();
  if (!kh) {
    float inv[2];
#pragma unroll
    for (int jq = 0; jq < 2; ++jq) inv[jq] = 1.f / (li[jq] + myRed[32 + jq]);
#pragma unroll
    for (int jd = 0; jd < 4; ++jd)
#pragma unroll
      for (int jq = 0; jq < 2; ++jq) {
        half4 ov;
#pragma unroll
        for (int r = 0; r < 4; ++r) {
          float v = Oacc[jd][jq][r] + myRed[jd * 8 + jq * 4 + r];
          ov[r] = (_Float16)(v * inv[jq]);
        }
        *(half4*)(O + ((size_t)b * T_SEQ + q0w + jq * 16 + ln) * D_MODEL +
                  h * 64 + jd * 16 + quad * 4) = ov;
      }
  }
}

extern "C" void kernel_launch(void* const* d_in, const int* in_sizes, int n_in,
                              void* d_out, int out_size, void* d_ws, size_t ws_size,
                              hipStream_t stream) {
  const void* x      = d_in[0];
  const void* amask  = d_in[1];
  const void* w_attn = d_in[2];
  const void* b_attn = d_in[3];
  const void* w_proj = d_in[4];
  const void* b_proj = d_in[5];
  const unsigned short* xdet = (const unsigned short*)x;

  char* ws = (char*)d_ws;
  size_t off = 0;
  auto alloc = [&](size_t bytes) {
    void* p = ws + off;
    off += (bytes + 255) & ~(size_t)255;
    return p;
  };
  _Float16* Xh     = (_Float16*)alloc((size_t)4096 * 1024 * 2);
  _Float16* WaT    = (_Float16*)alloc((size_t)3072 * 1024 * 2);
  _Float16* WpT    = (_Float16*)alloc((size_t)1024 * 1024 * 2);
  float* baF       = (float*)alloc(3072 * 4);
  float* bpF       = (float*)alloc(1024 * 4);
  float* mask2     = (float*)alloc(4096 * 4);
  _Float16* Qs     = (_Float16*)alloc((size_t)4096 * 1024 * 2);
  _Float16* Ks     = (_Float16*)alloc((size_t)4096 * 1024 * 2);
  _Float16* Vt     = (_Float16*)alloc((size_t)4096 * 1024 * 2);
  _Float16* AttnH  = (_Float16*)alloc((size_t)4096 * 1024 * 2);

  // transpose + bias/mask cvt + x->fp16, one launch (4128 + 2048 blocks)
  k_transpose2<<<3072 + 1024 + 32 + 2048, 256, 0, stream>>>(
      w_attn, WaT, w_proj, WpT, b_attn, b_proj, amask, baF, bpF, mask2, x, Xh, xdet);

  // GEMM1: qkv^T = WaT(3072xK) . Xh(4096xK)^T (pure-DMA B), fused scatter
  dim3 g1(4096 / 128, 3072 / 128);
  k_gemm<<<g1, 256, 0, stream>>>(WaT, Xh, baF, Qs, Ks, Vt, 3072, 4096, 1024, 0, 0, xdet);

  k_flash<<<1024, 256, 0, stream>>>(Qs, Ks, Vt, mask2, AttnH);

  // GEMM2: out^T = WpT(1024xK) . AttnH(4096xK)^T -> d_out [t][1024], 64^2 tiles
  dim3 g2(4096 / 64, 1024 / 64);
  k_gemm64<<<g2, 256, 0, stream>>>(WpT, AttnH, bpF, d_out, 1024, 4096, 1024, xdet);
}